// Round 2
// baseline (241.750 us; speedup 1.0000x reference)
//
#include <hip/hip_runtime.h>

#define B_ 32
#define C_ 128
#define H_ 56
#define W_ 56
#define HW_ (H_*W_)            // 3136
#define SIZE_ (C_*HW_)         // 401408
#define NPIX_ (B_*HW_)         // 100352 = 784 * 128
#define HP_ 58
#define WP_ 58
#define PLANE_ (HP_*WP_*C_)    // 430592 bf16 elements per batch plane
#define K_ 1152                // 9 * 128
#define EPS_ 1e-5f
#define SLOPE_ 0.1f

typedef __bf16 bf16x8 __attribute__((ext_vector_type(8)));
typedef float  f32x4  __attribute__((ext_vector_type(4)));

__device__ __forceinline__ ushort f2bf(float x) {
    union { float f; unsigned u; } v; v.f = x;
    return (ushort)((v.u + 0x7FFFu + ((v.u >> 16) & 1u)) >> 16);   // RNE
}
__device__ __forceinline__ float lrelu(float z) { return z > 0.f ? z : SLOPE_ * z; }

// async global->LDS, 16B per lane; LDS dest = wave-uniform base + lane*16
__device__ __forceinline__ void glds16(const ushort* g, ushort* l) {
    __builtin_amdgcn_global_load_lds(
        (const __attribute__((address_space(1))) unsigned int*)g,
        (__attribute__((address_space(3))) unsigned int*)l, 16, 0, 0);
}

// ---------------------------------------------------------------------------
// prep: repack conv_w -> bf16 wA[co][k], k=(kh*3+kw)*128+ci; fold bias+BN2;
//       fold BN1 into per-position mix params p0,p1,p2.
// ---------------------------------------------------------------------------
__global__ __launch_bounds__(256) void prep_kernel(
    const float* __restrict__ conv_w, const float* __restrict__ conv_b,
    const float* __restrict__ g2, const float* __restrict__ b2,
    const float* __restrict__ m2, const float* __restrict__ v2,
    const float2* __restrict__ cfc, const float* __restrict__ g1,
    const float* __restrict__ b1, const float* __restrict__ mu1,
    const float* __restrict__ v1,
    ushort* __restrict__ wA, float* __restrict__ scale2, float* __restrict__ shift2,
    float* __restrict__ p0, float* __restrict__ p1, float* __restrict__ p2)
{
    int tid = blockIdx.x * 256 + threadIdx.x;
    if (tid < C_ * K_) {
        int co = tid / K_;
        int k  = tid - co * K_;
        int khkw = k >> 7, ci = k & 127;
        int kh = khkw / 3, kw = khkw - 3 * kh;
        wA[tid] = f2bf(conv_w[((co * C_ + ci) * 3 + kh) * 3 + kw]);
    }
    if (tid < C_) {
        float sc = g2[tid] * rsqrtf(v2[tid] + EPS_);
        scale2[tid] = sc;
        shift2[tid] = (conv_b[tid] - m2[tid]) * sc + b2[tid];
    }
    if (tid < SIZE_) {
        float sc = g1[tid] * rsqrtf(v1[tid] + EPS_);
        float2 wv = cfc[tid];
        p0[tid] = wv.x * sc;
        p1[tid] = wv.y * sc;
        p2[tid] = b1[tid] - mu1[tid] * sc;
    }
}

// ---------------------------------------------------------------------------
// zfuse: z = leaky(a*p0 + m*p1 + p2) -> bf16 NHWC zero-padded [32][58][58][128]
// one block per (b, padded row). float4 loads, LDS transpose (stride 132),
// uint2 coalesced write-out.
// ---------------------------------------------------------------------------
__global__ __launch_bounds__(256) void zfuse_kernel(
    const float4* __restrict__ ax, const float4* __restrict__ mx,
    const float4* __restrict__ p0, const float4* __restrict__ p1,
    const float4* __restrict__ p2, ushort* __restrict__ zp)
{
    __shared__ ushort tile[W_ * 132];   // stride 132: 8B-aligned rows, no 2^k banking
    const int hp = blockIdx.x, b = blockIdx.y;
    const int tid = threadIdx.x;
    ushort* row = zp + (size_t)b * PLANE_ + (size_t)hp * (WP_ * C_);
    if (hp == 0 || hp == HP_ - 1) {            // full zero border rows
        uint2* r2 = (uint2*)row;
        for (int i = tid; i < WP_ * C_ / 4; i += 256) r2[i] = make_uint2(0u, 0u);
        return;
    }
    const int h = hp - 1;
    const int base4 = (b * SIZE_) >> 2;
    for (int i = tid; i < 1792; i += 256) {    // 128 c * 14 float4-groups
        int c  = i / 14;
        int w4 = i - c * 14;
        int s4 = c * (HW_ / 4) + h * (W_ / 4) + w4;   // float4 index into [SIZE_]
        float4 a = ax[base4 + s4];
        float4 m = mx[base4 + s4];
        float4 q0 = p0[s4], q1 = p1[s4], q2 = p2[s4];
        int wb = w4 * 4;
        tile[(wb + 0) * 132 + c] = f2bf(lrelu(a.x * q0.x + m.x * q1.x + q2.x));
        tile[(wb + 1) * 132 + c] = f2bf(lrelu(a.y * q0.y + m.y * q1.y + q2.y));
        tile[(wb + 2) * 132 + c] = f2bf(lrelu(a.z * q0.z + m.z * q1.z + q2.z));
        tile[(wb + 3) * 132 + c] = f2bf(lrelu(a.w * q0.w + m.w * q1.w + q2.w));
    }
    __syncthreads();
    if (tid < C_) {                            // left/right border columns
        row[tid] = 0;
        row[(WP_ - 1) * C_ + tid] = 0;
    }
    for (int j = tid; j < 1792; j += 256) {    // 56 w * 32 uint2-chunks
        int w = j >> 5, cc = j & 31;
        *(uint2*)(row + C_ + w * C_ + cc * 4) = *(const uint2*)(tile + w * 132 + cc * 4);
    }
}

// ---------------------------------------------------------------------------
// conv: implicit GEMM, M=128co x N=100352px x K=1152, bf16 MFMA 16x16x32.
// 128x128 tile, BK=32, THREE-buffer LDS rotation (48KB), stage distance 2,
// COUNTED vmcnt + raw s_barrier (T3+T4): loads for steps t+1,t+2 stay in
// flight ACROSS barriers -- never drain vmcnt to 0 in the main loop.
// Step t: vmcnt(4) [step t's stage retired] ; s_barrier ; sched_barrier(0) ;
//         stage(t+2 -> buf[(t+2)%3])  [that buf was read at t-1; all waves'
//         t-1 ds_reads retired before they reached this barrier] ;
//         ds_read buf[t%3] ; 16x MFMA  (compiler inserts lgkmcnt).
// XOR source-preswizzle retained (bank-conflict-free ds_read_b128).
// ---------------------------------------------------------------------------
__global__ __launch_bounds__(256, 3) void conv_kernel(
    const ushort* __restrict__ zp, const ushort* __restrict__ wA,
    const float* __restrict__ scale2, const float* __restrict__ shift2,
    float* __restrict__ out)
{
    __shared__ ushort As[3][128 * 32];   // 3 x 8 KB
    __shared__ ushort Bs[3][128 * 32];   // 3 x 8 KB

    const int tid  = threadIdx.x;
    const int wave = tid >> 6, lane = tid & 63;
    const int l16  = lane & 15, quad = lane >> 4;
    const int pbase = blockIdx.x * 128;

    // ---- staging roles: each wave stages 32 rows (2 glds of 16 rows) ----
    const int srow = wave * 32 + (lane >> 2);     // LDS row for instr 0 (+16 for instr 1)
    const int skey = (srow >> 1) & 3;             // swizzle key; invariant under row+16
    const int sch  = (lane & 3) ^ skey;           // swizzled 16B source chunk in 64B row
    const ushort* agA = wA + srow * K_ + sch * 8; // A: weights (+16*K_ for instr 1)

    int pf0 = pbase + srow;
    int bb0 = pf0 / HW_, pi0 = pf0 - bb0 * HW_;
    int h0 = pi0 / W_, w0 = pi0 - h0 * W_;
    const ushort* bgB0 = zp + (size_t)bb0 * PLANE_ + (h0 * WP_ + w0) * C_ + sch * 8;
    int pf1 = pf0 + 16;
    int bb1 = pf1 / HW_, pi1 = pf1 - bb1 * HW_;
    int h1 = pi1 / W_, w1 = pi1 - h1 * W_;
    const ushort* bgB1 = zp + (size_t)bb1 * PLANE_ + (h1 * WP_ + w1) * C_ + sch * 8;

    const int lofs0 = (wave * 32) * 32;           // wave-uniform LDS dests (linear!)
    const int lofs1 = (wave * 32 + 16) * 32;

    // ---- compute roles: wave = 64co x 64px quadrant ----
    const int cob = (wave & 1) * 64;
    const int pxb = (wave >> 1) * 64;
    // read-side swizzle: key of row (cob/pxb + mt*16 + l16) reduces to (l16>>1)&3
    const int rquad = quad ^ ((l16 >> 1) & 3);

    f32x4 acc[4][4] = {};

#define STAGE(buf, aoff, boff)                                    \
    do {                                                          \
        glds16(agA + (aoff),           As[buf] + lofs0);          \
        glds16(agA + 16 * K_ + (aoff), As[buf] + lofs1);          \
        glds16(bgB0 + (boff),          Bs[buf] + lofs0);          \
        glds16(bgB1 + (boff),          Bs[buf] + lofs1);          \
    } while (0)

    // B byte offset of K-step t (tap = t>>2, ks = t&3) -- constant under unroll
#define BOFF(t) ((((t) >> 2) / 3 * WP_ + ((t) >> 2) % 3) * C_ + ((t) & 3) * 32)

    // prologue: stage steps 0 and 1 (8 loads in flight)
    STAGE(0, 0, BOFF(0));
    STAGE(1, 32, BOFF(1));

    #pragma unroll
    for (int t = 0; t < 36; ++t) {
        // counted wait: step t's 4 loads retired; step t+1's 4 stay in flight
        if (t < 35) asm volatile("s_waitcnt vmcnt(4)" ::: "memory");
        else        asm volatile("s_waitcnt vmcnt(0)" ::: "memory");
        __builtin_amdgcn_s_barrier();            // raw barrier -- no drain
        __builtin_amdgcn_sched_barrier(0);       // pin: nothing hoists above
        if (t <= 33) {
            const int t2 = t + 2;
            STAGE(t2 % 3, t2 * 32, BOFF(t2));    // into buf last read at t-1
        }
        const int buf = t % 3;
        bf16x8 af[4], bfr[4];
        #pragma unroll
        for (int mt = 0; mt < 4; ++mt)
            af[mt] = *(const bf16x8*)(As[buf] + (cob + mt * 16 + l16) * 32 + rquad * 8);
        #pragma unroll
        for (int nt = 0; nt < 4; ++nt)
            bfr[nt] = *(const bf16x8*)(Bs[buf] + (pxb + nt * 16 + l16) * 32 + rquad * 8);
        #pragma unroll
        for (int mt = 0; mt < 4; ++mt)
            #pragma unroll
            for (int nt = 0; nt < 4; ++nt)
                acc[mt][nt] = __builtin_amdgcn_mfma_f32_16x16x32_bf16(
                    af[mt], bfr[nt], acc[mt][nt], 0, 0, 0);
    }
#undef STAGE
#undef BOFF

    // ---- epilogue: fused scale/shift + leaky, NCHW fp32 stores ----
    int pob[4];
    #pragma unroll
    for (int nt = 0; nt < 4; ++nt) {
        int pf = pbase + pxb + nt * 16 + l16;
        int bb = pf / HW_;
        pob[nt] = bb * SIZE_ + (pf - bb * HW_);
    }
    #pragma unroll
    for (int mt = 0; mt < 4; ++mt) {
        #pragma unroll
        for (int r = 0; r < 4; ++r) {
            int co = cob + mt * 16 + quad * 4 + r;
            float sc = scale2[co], sh = shift2[co];
            #pragma unroll
            for (int nt = 0; nt < 4; ++nt) {
                float v = acc[mt][nt][r] * sc + sh;
                out[(size_t)pob[nt] + co * HW_] = lrelu(v);
            }
        }
    }
}

// ---------------------------------------------------------------------------
extern "C" void kernel_launch(void* const* d_in, const int* in_sizes, int n_in,
                              void* d_out, int out_size, void* d_ws, size_t ws_size,
                              hipStream_t stream) {
    const float* ax     = (const float*)d_in[0];
    const float* mx     = (const float*)d_in[1];
    const float* cfc    = (const float*)d_in[2];
    const float* bn_g   = (const float*)d_in[3];
    const float* bn_b   = (const float*)d_in[4];
    const float* bn_m   = (const float*)d_in[5];
    const float* bn_v   = (const float*)d_in[6];
    const float* conv_w = (const float*)d_in[7];
    const float* conv_b = (const float*)d_in[8];
    const float* g2     = (const float*)d_in[9];
    const float* b2     = (const float*)d_in[10];
    const float* m2     = (const float*)d_in[11];
    const float* v2     = (const float*)d_in[12];
    float* out = (float*)d_out;

    char* ws = (char*)d_ws;
    // zp: 27,557,888 B | wA: 294,912 B | scale2/shift2: 512 B each | p0/p1/p2: 1,605,632 B each
    ushort* zp     = (ushort*)ws;
    ushort* wA     = (ushort*)(ws + 27557888);
    float*  scale2 = (float*)(ws + 27852800);
    float*  shift2 = (float*)(ws + 27853312);
    float*  p0     = (float*)(ws + 27853824);
    float*  p1     = (float*)(ws + 29459456);
    float*  p2     = (float*)(ws + 31065088);

    prep_kernel<<<dim3((SIZE_ + 255) / 256), 256, 0, stream>>>(
        conv_w, conv_b, g2, b2, m2, v2, (const float2*)cfc,
        bn_g, bn_b, bn_m, bn_v, wA, scale2, shift2, p0, p1, p2);
    zfuse_kernel<<<dim3(HP_, B_), 256, 0, stream>>>(
        (const float4*)ax, (const float4*)mx,
        (const float4*)p0, (const float4*)p1, (const float4*)p2, zp);
    conv_kernel<<<dim3(NPIX_ / 128), 256, 0, stream>>>(zp, wA, scale2, shift2, out);
}

// Round 3
// 237.209 us; speedup vs baseline: 1.0191x; 1.0191x over previous
//
#include <hip/hip_runtime.h>

#define B_ 32
#define C_ 128
#define H_ 56
#define W_ 56
#define HW_ (H_*W_)            // 3136
#define SIZE_ (C_*HW_)         // 401408
#define NPIX_ (B_*HW_)         // 100352 = 784 * 128
#define HP_ 58
#define WP_ 58
#define PLSZ_ (B_*HP_*WP_*32)  // 3,444,736 ushort per 32-channel chunk plane
#define K_ 1152                // 9 * 128
#define EPS_ 1e-5f
#define SLOPE_ 0.1f

typedef __bf16 bf16x8 __attribute__((ext_vector_type(8)));
typedef float  f32x4  __attribute__((ext_vector_type(4)));

__device__ __forceinline__ ushort f2bf(float x) {
    union { float f; unsigned u; } v; v.f = x;
    return (ushort)((v.u + 0x7FFFu + ((v.u >> 16) & 1u)) >> 16);   // RNE
}
__device__ __forceinline__ float lrelu(float z) { return z > 0.f ? z : SLOPE_ * z; }

// async global->LDS, 16B per lane; LDS dest = wave-uniform base + lane*16
__device__ __forceinline__ void glds16(const ushort* g, ushort* l) {
    __builtin_amdgcn_global_load_lds(
        (const __attribute__((address_space(1))) unsigned int*)g,
        (__attribute__((address_space(3))) unsigned int*)l, 16, 0, 0);
}

// ---------------------------------------------------------------------------
// prep: repack conv_w -> bf16 wA2[step][co][32k]  (step = tap*4 + ks, k-chunk
// contiguous per step: 8KB blocks -> full-line staging transactions);
// fold bias+BN2; fold BN1 into per-position mix params p0,p1,p2.
// ---------------------------------------------------------------------------
__global__ __launch_bounds__(256) void prep_kernel(
    const float* __restrict__ conv_w, const float* __restrict__ conv_b,
    const float* __restrict__ g2, const float* __restrict__ b2,
    const float* __restrict__ m2, const float* __restrict__ v2,
    const float2* __restrict__ cfc, const float* __restrict__ g1,
    const float* __restrict__ b1, const float* __restrict__ mu1,
    const float* __restrict__ v1,
    ushort* __restrict__ wA, float* __restrict__ scale2, float* __restrict__ shift2,
    float* __restrict__ p0, float* __restrict__ p1, float* __restrict__ p2)
{
    int tid = blockIdx.x * 256 + threadIdx.x;
    if (tid < C_ * K_) {
        int co = tid / K_;
        int k  = tid - co * K_;           // k = tap*128 + ks*32 + kk = t*32 + kk
        int t  = k >> 5, kk = k & 31;
        int khkw = k >> 7, ci = k & 127;
        int kh = khkw / 3, kw = khkw - 3 * kh;
        wA[(t * C_ + co) * 32 + kk] = f2bf(conv_w[((co * C_ + ci) * 3 + kh) * 3 + kw]);
    }
    if (tid < C_) {
        float sc = g2[tid] * rsqrtf(v2[tid] + EPS_);
        scale2[tid] = sc;
        shift2[tid] = (conv_b[tid] - m2[tid]) * sc + b2[tid];
    }
    if (tid < SIZE_) {
        float sc = g1[tid] * rsqrtf(v1[tid] + EPS_);
        float2 wv = cfc[tid];
        p0[tid] = wv.x * sc;
        p1[tid] = wv.y * sc;
        p2[tid] = b1[tid] - mu1[tid] * sc;
    }
}

// ---------------------------------------------------------------------------
// zfuse: z = leaky(a*p0 + m*p1 + p2) -> bf16, FOUR zero-padded 32-channel
// chunk planes zp2[ks][b][hp][wp][32] so a conv K-step's B-tile is contiguous
// 64B/pixel over consecutive pixels. Same total bytes as before.
// ---------------------------------------------------------------------------
__global__ __launch_bounds__(256) void zfuse_kernel(
    const float4* __restrict__ ax, const float4* __restrict__ mx,
    const float4* __restrict__ p0, const float4* __restrict__ p1,
    const float4* __restrict__ p2, ushort* __restrict__ zp)
{
    __shared__ ushort tile[W_ * 132];   // stride 132: 8B-aligned rows, no 2^k banking
    const int hp = blockIdx.x, b = blockIdx.y;
    const int tid = threadIdx.x;
    const int rb = (b * HP_ + hp) * (WP_ * 32);     // row base (ushort) within a plane
    if (hp == 0 || hp == HP_ - 1) {                 // full zero border rows, all 4 planes
        for (int ks = 0; ks < 4; ++ks) {
            uint2* r2 = (uint2*)(zp + ks * PLSZ_ + rb);
            for (int i = tid; i < WP_ * 32 / 4; i += 256) r2[i] = make_uint2(0u, 0u);
        }
        return;
    }
    const int h = hp - 1;
    const int base4 = (b * SIZE_) >> 2;
    for (int i = tid; i < 1792; i += 256) {    // 128 c * 14 float4-groups
        int c  = i / 14;
        int w4 = i - c * 14;
        int s4 = c * (HW_ / 4) + h * (W_ / 4) + w4;   // float4 index into [SIZE_]
        float4 a = ax[base4 + s4];
        float4 m = mx[base4 + s4];
        float4 q0 = p0[s4], q1 = p1[s4], q2 = p2[s4];
        int wb = w4 * 4;
        tile[(wb + 0) * 132 + c] = f2bf(lrelu(a.x * q0.x + m.x * q1.x + q2.x));
        tile[(wb + 1) * 132 + c] = f2bf(lrelu(a.y * q0.y + m.y * q1.y + q2.y));
        tile[(wb + 2) * 132 + c] = f2bf(lrelu(a.z * q0.z + m.z * q1.z + q2.z));
        tile[(wb + 3) * 132 + c] = f2bf(lrelu(a.w * q0.w + m.w * q1.w + q2.w));
    }
    __syncthreads();
    {   // left/right border columns: 4 planes x 32 ch x 2 sides = 256 threads
        int side = (tid >> 7) & 1, ks = (tid >> 5) & 3, cc = tid & 31;
        zp[ks * PLSZ_ + rb + (side ? (WP_ - 1) * 32 : 0) + cc] = 0;
    }
    for (int j = tid; j < 1792; j += 256) {    // 4 planes * 56 w * 8 uint2-chunks
        int ks = j / 448, r = j - ks * 448;
        int w = r >> 3, cc = r & 7;
        *(uint2*)(zp + ks * PLSZ_ + rb + (w + 1) * 32 + cc * 4) =
            *(const uint2*)(tile + w * 132 + ks * 32 + cc * 4);
    }
}

// ---------------------------------------------------------------------------
// conv: implicit GEMM, M=128co x N=100352px x K=1152, bf16 MFMA 16x16x32.
// 128x128 tile, BK=32, 3-buffer LDS, counted vmcnt pipeline (unchanged from
// R2).  NEW: step-major wA2 + k-chunk-plane zp2 make every staging glds16
// cover contiguous 1KB (full 128B lines) instead of 16 scattered 64B slices
// -> 2x fewer VMEM transactions, 4x fewer line touches per step.
// XCD-aware block swizzle (784 = 8*98, bijective) for zp/wA L2 locality.
// ---------------------------------------------------------------------------
__global__ __launch_bounds__(256, 3) void conv_kernel(
    const ushort* __restrict__ zp, const ushort* __restrict__ wA,
    const float* __restrict__ scale2, const float* __restrict__ shift2,
    float* __restrict__ out)
{
    __shared__ ushort As[3][128 * 32];   // 3 x 8 KB
    __shared__ ushort Bs[3][128 * 32];   // 3 x 8 KB

    const int tid  = threadIdx.x;
    const int wave = tid >> 6, lane = tid & 63;
    const int l16  = lane & 15, quad = lane >> 4;
    // XCD swizzle: 784 blocks = 8 XCDs x 98 contiguous
    const int bid  = blockIdx.x;
    const int pbase = ((bid & 7) * 98 + (bid >> 3)) * 128;

    // ---- staging roles: each wave stages 32 rows (2 glds of 16 rows) ----
    const int srow = wave * 32 + (lane >> 2);     // LDS row for instr 0 (+16 for instr 1)
    const int skey = (srow >> 1) & 3;             // swizzle key; invariant under row+16
    const int sch  = (lane & 3) ^ skey;           // swizzled 16B chunk within 64B row
    const ushort* agA = wA + srow * 32 + sch * 8; // step t adds t*4096 (contiguous 8KB)

    int pf0 = pbase + srow;
    int bb0 = pf0 / HW_, pi0 = pf0 - bb0 * HW_;
    int h0 = pi0 / W_, w0 = pi0 - h0 * W_;
    const ushort* bgB0 = zp + ((bb0 * HP_ + h0) * WP_ + w0) * 32 + sch * 8;
    int pf1 = pf0 + 16;
    int bb1 = pf1 / HW_, pi1 = pf1 - bb1 * HW_;
    int h1 = pi1 / W_, w1 = pi1 - h1 * W_;
    const ushort* bgB1 = zp + ((bb1 * HP_ + h1) * WP_ + w1) * 32 + sch * 8;

    const int lofs0 = (wave * 32) * 32;           // wave-uniform LDS dests (linear!)
    const int lofs1 = (wave * 32 + 16) * 32;

    // ---- compute roles: wave = 64co x 64px quadrant ----
    const int cob = (wave & 1) * 64;
    const int pxb = (wave >> 1) * 64;
    // read-side swizzle: key of row (cob/pxb + mt*16 + l16) reduces to (l16>>1)&3
    const int rquad = quad ^ ((l16 >> 1) & 3);

    f32x4 acc[4][4] = {};

#define STAGE(buf, t)                                                      \
    do {                                                                   \
        glds16(agA + (t) * 4096,        As[buf] + lofs0);                  \
        glds16(agA + (t) * 4096 + 512,  As[buf] + lofs1);                  \
        glds16(bgB0 + BOFF(t),          Bs[buf] + lofs0);                  \
        glds16(bgB1 + BOFF(t),          Bs[buf] + lofs1);                  \
    } while (0)

    // B offset of K-step t: plane (t&3), tap shift (kh*WP+kw)*32 -- constants
#define BOFF(t) (((t) & 3) * PLSZ_ + (((((t) >> 2) / 3) * WP_ + (((t) >> 2) % 3)) * 32))

    // prologue: stage steps 0 and 1 (8 loads in flight)
    STAGE(0, 0);
    STAGE(1, 1);

    #pragma unroll
    for (int t = 0; t < 36; ++t) {
        // counted wait: step t's 4 loads retired; step t+1's 4 stay in flight
        if (t < 35) asm volatile("s_waitcnt vmcnt(4)" ::: "memory");
        else        asm volatile("s_waitcnt vmcnt(0)" ::: "memory");
        __builtin_amdgcn_s_barrier();            // raw barrier -- no drain
        __builtin_amdgcn_sched_barrier(0);       // pin: nothing hoists above
        if (t <= 33) {
            STAGE((t + 2) % 3, t + 2);           // into buf last read at t-1
        }
        const int buf = t % 3;
        bf16x8 af[4], bfr[4];
        #pragma unroll
        for (int mt = 0; mt < 4; ++mt)
            af[mt] = *(const bf16x8*)(As[buf] + (cob + mt * 16 + l16) * 32 + rquad * 8);
        #pragma unroll
        for (int nt = 0; nt < 4; ++nt)
            bfr[nt] = *(const bf16x8*)(Bs[buf] + (pxb + nt * 16 + l16) * 32 + rquad * 8);
        #pragma unroll
        for (int mt = 0; mt < 4; ++mt)
            #pragma unroll
            for (int nt = 0; nt < 4; ++nt)
                acc[mt][nt] = __builtin_amdgcn_mfma_f32_16x16x32_bf16(
                    af[mt], bfr[nt], acc[mt][nt], 0, 0, 0);
    }
#undef STAGE
#undef BOFF

    // ---- epilogue: fused scale/shift + leaky, NCHW fp32 stores ----
    int pob[4];
    #pragma unroll
    for (int nt = 0; nt < 4; ++nt) {
        int pf = pbase + pxb + nt * 16 + l16;
        int bb = pf / HW_;
        pob[nt] = bb * SIZE_ + (pf - bb * HW_);
    }
    #pragma unroll
    for (int mt = 0; mt < 4; ++mt) {
        #pragma unroll
        for (int r = 0; r < 4; ++r) {
            int co = cob + mt * 16 + quad * 4 + r;
            float sc = scale2[co], sh = shift2[co];
            #pragma unroll
            for (int nt = 0; nt < 4; ++nt) {
                float v = acc[mt][nt][r] * sc + sh;
                out[(size_t)pob[nt] + co * HW_] = lrelu(v);
            }
        }
    }
}

// ---------------------------------------------------------------------------
extern "C" void kernel_launch(void* const* d_in, const int* in_sizes, int n_in,
                              void* d_out, int out_size, void* d_ws, size_t ws_size,
                              hipStream_t stream) {
    const float* ax     = (const float*)d_in[0];
    const float* mx     = (const float*)d_in[1];
    const float* cfc    = (const float*)d_in[2];
    const float* bn_g   = (const float*)d_in[3];
    const float* bn_b   = (const float*)d_in[4];
    const float* bn_m   = (const float*)d_in[5];
    const float* bn_v   = (const float*)d_in[6];
    const float* conv_w = (const float*)d_in[7];
    const float* conv_b = (const float*)d_in[8];
    const float* g2     = (const float*)d_in[9];
    const float* b2     = (const float*)d_in[10];
    const float* m2     = (const float*)d_in[11];
    const float* v2     = (const float*)d_in[12];
    float* out = (float*)d_out;

    char* ws = (char*)d_ws;
    // zp2: 4 planes x 6,889,472 B = 27,557,888 B | wA2: 294,912 B | scale2/shift2 | p0/p1/p2
    ushort* zp     = (ushort*)ws;
    ushort* wA     = (ushort*)(ws + 27557888);
    float*  scale2 = (float*)(ws + 27852800);
    float*  shift2 = (float*)(ws + 27853312);
    float*  p0     = (float*)(ws + 27853824);
    float*  p1     = (float*)(ws + 29459456);
    float*  p2     = (float*)(ws + 31065088);

    prep_kernel<<<dim3((SIZE_ + 255) / 256), 256, 0, stream>>>(
        conv_w, conv_b, g2, b2, m2, v2, (const float2*)cfc,
        bn_g, bn_b, bn_m, bn_v, wA, scale2, shift2, p0, p1, p2);
    zfuse_kernel<<<dim3(HP_, B_), 256, 0, stream>>>(
        (const float4*)ax, (const float4*)mx,
        (const float4*)p0, (const float4*)p1, (const float4*)p2, zp);
    conv_kernel<<<dim3(NPIX_ / 128), 256, 0, stream>>>(zp, wA, scale2, shift2, out);
}

// Round 4
// 230.675 us; speedup vs baseline: 1.0480x; 1.0283x over previous
//
#include <hip/hip_runtime.h>

#define B_ 32
#define C_ 128
#define H_ 56
#define W_ 56
#define HW_ (H_*W_)            // 3136
#define SIZE_ (C_*HW_)         // 401408
#define NPIX_ (B_*HW_)         // 100352 = 392 * 256
#define HP_ 58
#define WP_ 58
#define PLSZ_ (B_*HP_*WP_*32)  // 3,444,736 ushort per 32-channel chunk plane
#define K_ 1152                // 9 * 128
#define EPS_ 1e-5f
#define SLOPE_ 0.1f

typedef __bf16 bf16x8 __attribute__((ext_vector_type(8)));
typedef float  f32x4  __attribute__((ext_vector_type(4)));

__device__ __forceinline__ ushort f2bf(float x) {
    union { float f; unsigned u; } v; v.f = x;
    return (ushort)((v.u + 0x7FFFu + ((v.u >> 16) & 1u)) >> 16);   // RNE
}
__device__ __forceinline__ float lrelu(float z) { return z > 0.f ? z : SLOPE_ * z; }

// async global->LDS, 16B per lane; LDS dest = wave-uniform base + lane*16
__device__ __forceinline__ void glds16(const ushort* g, ushort* l) {
    __builtin_amdgcn_global_load_lds(
        (const __attribute__((address_space(1))) unsigned int*)g,
        (__attribute__((address_space(3))) unsigned int*)l, 16, 0, 0);
}

// ---------------------------------------------------------------------------
// prep: repack conv_w -> bf16 wA3[t18][co128][64k]  (K-tile t = k/64: each
// tile's 128x64 A-slice is one contiguous 16KB block); fold bias+BN2;
// fold BN1 into per-position mix params p0,p1,p2.
// ---------------------------------------------------------------------------
__global__ __launch_bounds__(256) void prep_kernel(
    const float* __restrict__ conv_w, const float* __restrict__ conv_b,
    const float* __restrict__ g2, const float* __restrict__ b2,
    const float* __restrict__ m2, const float* __restrict__ v2,
    const float2* __restrict__ cfc, const float* __restrict__ g1,
    const float* __restrict__ b1, const float* __restrict__ mu1,
    const float* __restrict__ v1,
    ushort* __restrict__ wA, float* __restrict__ scale2, float* __restrict__ shift2,
    float* __restrict__ p0, float* __restrict__ p1, float* __restrict__ p2)
{
    int tid = blockIdx.x * 256 + threadIdx.x;
    if (tid < C_ * K_) {
        int co = tid / K_;
        int k  = tid - co * K_;           // k = tap*128 + ci
        int khkw = k >> 7, ci = k & 127;
        int kh = khkw / 3, kw = khkw - 3 * kh;
        wA[((k >> 6) * C_ + co) * 64 + (k & 63)] =
            f2bf(conv_w[((co * C_ + ci) * 3 + kh) * 3 + kw]);
    }
    if (tid < C_) {
        float sc = g2[tid] * rsqrtf(v2[tid] + EPS_);
        scale2[tid] = sc;
        shift2[tid] = (conv_b[tid] - m2[tid]) * sc + b2[tid];
    }
    if (tid < SIZE_) {
        float sc = g1[tid] * rsqrtf(v1[tid] + EPS_);
        float2 wv = cfc[tid];
        p0[tid] = wv.x * sc;
        p1[tid] = wv.y * sc;
        p2[tid] = b1[tid] - mu1[tid] * sc;
    }
}

// ---------------------------------------------------------------------------
// zfuse: z = leaky(a*p0 + m*p1 + p2) -> bf16, FOUR zero-padded 32-channel
// chunk planes zp2[kc][b][hp][wp][32] (kc = ci>>5). Unchanged from R3.
// ---------------------------------------------------------------------------
__global__ __launch_bounds__(256) void zfuse_kernel(
    const float4* __restrict__ ax, const float4* __restrict__ mx,
    const float4* __restrict__ p0, const float4* __restrict__ p1,
    const float4* __restrict__ p2, ushort* __restrict__ zp)
{
    __shared__ ushort tile[W_ * 132];   // stride 132: 8B-aligned rows, no 2^k banking
    const int hp = blockIdx.x, b = blockIdx.y;
    const int tid = threadIdx.x;
    const int rb = (b * HP_ + hp) * (WP_ * 32);     // row base (ushort) within a plane
    if (hp == 0 || hp == HP_ - 1) {                 // full zero border rows, all 4 planes
        for (int ks = 0; ks < 4; ++ks) {
            uint2* r2 = (uint2*)(zp + ks * PLSZ_ + rb);
            for (int i = tid; i < WP_ * 32 / 4; i += 256) r2[i] = make_uint2(0u, 0u);
        }
        return;
    }
    const int h = hp - 1;
    const int base4 = (b * SIZE_) >> 2;
    for (int i = tid; i < 1792; i += 256) {    // 128 c * 14 float4-groups
        int c  = i / 14;
        int w4 = i - c * 14;
        int s4 = c * (HW_ / 4) + h * (W_ / 4) + w4;   // float4 index into [SIZE_]
        float4 a = ax[base4 + s4];
        float4 m = mx[base4 + s4];
        float4 q0 = p0[s4], q1 = p1[s4], q2 = p2[s4];
        int wb = w4 * 4;
        tile[(wb + 0) * 132 + c] = f2bf(lrelu(a.x * q0.x + m.x * q1.x + q2.x));
        tile[(wb + 1) * 132 + c] = f2bf(lrelu(a.y * q0.y + m.y * q1.y + q2.y));
        tile[(wb + 2) * 132 + c] = f2bf(lrelu(a.z * q0.z + m.z * q1.z + q2.z));
        tile[(wb + 3) * 132 + c] = f2bf(lrelu(a.w * q0.w + m.w * q1.w + q2.w));
    }
    __syncthreads();
    {   // left/right border columns: 4 planes x 32 ch x 2 sides = 256 threads
        int side = (tid >> 7) & 1, ks = (tid >> 5) & 3, cc = tid & 31;
        zp[ks * PLSZ_ + rb + (side ? (WP_ - 1) * 32 : 0) + cc] = 0;
    }
    for (int j = tid; j < 1792; j += 256) {    // 4 planes * 56 w * 8 uint2-chunks
        int ks = j / 448, r = j - ks * 448;
        int w = r >> 3, cc = r & 7;
        *(uint2*)(zp + ks * PLSZ_ + rb + (w + 1) * 32 + cc * 4) =
            *(const uint2*)(tile + w * 132 + ks * 32 + cc * 4);
    }
}

// ---------------------------------------------------------------------------
// conv: implicit GEMM, M=128co x N=100352px x K=1152, bf16 MFMA 16x16x32.
// m201-class deep pipeline: 512 threads (8 waves, 2co x 4px), tile 128x256,
// BK=64 (18 K-tiles), THREE-buffer LDS (144KB, 1 block/CU), one barrier per
// K-tile.  Per tile t:
//   vmcnt(6)  [own stage(t) retired; stage(t+1)'s 6 stay in flight]  ->
//   s_barrier [certifies ALL waves' stage(t) retired; all t-1 reads done] ->
//   STAGE(t+2 -> buf[(t+2)%3]) -> ds_read buf[t%3] + 32 MFMA (setprio 1).
// Issue-to-wait distance = 2 K-tiles (~2500 cyc) >> load latency; vmcnt never
// drains to 0 in the main loop (T4).  XOR chunk-swizzle on staging SOURCE +
// matching read swizzle: ds_read_b128 at 2-way (free) bank aliasing.
// ---------------------------------------------------------------------------
__global__ __launch_bounds__(512, 2) void conv_kernel(
    const ushort* __restrict__ zp, const ushort* __restrict__ wA,
    const float* __restrict__ scale2, const float* __restrict__ shift2,
    float* __restrict__ out)
{
    __shared__ ushort As[3][128 * 64];   // 3 x 16 KB
    __shared__ ushort Bs[3][256 * 64];   // 3 x 32 KB

    const int tid  = threadIdx.x;
    const int wave = tid >> 6, lane = tid & 63;
    const int l16  = lane & 15, quad = lane >> 4;
    // XCD swizzle: 392 blocks = 8 XCDs x 49 contiguous
    const int bid  = blockIdx.x;
    const int pbase = ((bid & 7) * 49 + (bid >> 3)) * 256;

    // ---- staging roles ----
    // A: wave stages co rows [16w,16w+16) as 2 glds of 8 rows (row = 128B).
    // B: wave stages px rows [32w,32w+32) as 4 glds of 8 rows.
    // chunk swizzle key: row&7 == (lane>>3)&7 for every glds (bases are x8).
    const int c_swz = (lane & 7) ^ ((lane >> 3) & 7);   // physical src chunk
    const ushort* agA = wA + (16 * wave + (lane >> 3)) * 64 + c_swz * 8;

    const ushort* bgB[4];
    #pragma unroll
    for (int j = 0; j < 4; ++j) {
        int pxl = 32 * wave + 8 * j + (lane >> 3);
        int pf  = pbase + pxl;
        int bb  = pf / HW_, pi = pf - bb * HW_;
        int h   = pi / W_, w = pi - h * W_;
        bgB[j] = zp + (c_swz >> 2) * PLSZ_
                    + ((bb * HP_ + h) * WP_ + w) * 32 + (c_swz & 3) * 8;
    }

    // ---- compute roles: wave = 64co x 64px of the 128x256 tile ----
    const int cob = (wave & 1) * 64;
    const int pxb = (wave >> 1) * 64;
    // read-side swizzle: physical chunk = (ks*4+quad) ^ (row&7), row&7 = l16&7
    const int ch0 = ((quad ^ (l16 & 7))) * 8;   // ks=0, ushort offset
    const int ch1 = ch0 ^ 32;                   // ks=1 ((c^4)*8 == c*8 ^ 32)

    f32x4 acc[4][4] = {};

    // B byte delta of K-tile t: plane pair 2*(t&1), tap shift (kh*WP+kw)*32
#define BDEL(t) (((t) & 1) * 2 * PLSZ_ + \
                 (((((t) >> 1) / 3) * WP_ + (((t) >> 1) % 3)) * 32))

#define STAGE(t, buf) do {                                              \
        glds16(agA + (t) * 8192,        &As[buf][wave * 1024]);         \
        glds16(agA + (t) * 8192 + 512,  &As[buf][wave * 1024 + 512]);   \
        glds16(bgB[0] + BDEL(t), &Bs[buf][wave * 2048]);                \
        glds16(bgB[1] + BDEL(t), &Bs[buf][wave * 2048 + 512]);          \
        glds16(bgB[2] + BDEL(t), &Bs[buf][wave * 2048 + 1024]);         \
        glds16(bgB[3] + BDEL(t), &Bs[buf][wave * 2048 + 1536]);         \
    } while (0)

    // prologue: stage K-tiles 0,1 (12 loads in flight)
    STAGE(0, 0);
    STAGE(1, 1);

    #pragma unroll
    for (int t = 0; t < 18; ++t) {
        __builtin_amdgcn_sched_barrier(0);
        // own stage(t) retired; stage(t+1) (6 loads) stays in flight
        if (t < 17) asm volatile("s_waitcnt vmcnt(6)" ::: "memory");
        else        asm volatile("s_waitcnt vmcnt(0)" ::: "memory");
        __builtin_amdgcn_s_barrier();    // all waves' stage(t) now visible
        __builtin_amdgcn_sched_barrier(0);
        if (t <= 15) STAGE(t + 2, (t + 2) % 3);   // buf last read at t-1

        const int buf = t % 3;
        bf16x8 af0[4], af1[4], bf0[4], bf1[4];
        #pragma unroll
        for (int mt = 0; mt < 4; ++mt) {
            const ushort* ar = &As[buf][(cob + mt * 16 + l16) * 64];
            af0[mt] = *(const bf16x8*)(ar + ch0);
            af1[mt] = *(const bf16x8*)(ar + ch1);
        }
        #pragma unroll
        for (int nt = 0; nt < 4; ++nt) {
            const ushort* br = &Bs[buf][(pxb + nt * 16 + l16) * 64];
            bf0[nt] = *(const bf16x8*)(br + ch0);
            bf1[nt] = *(const bf16x8*)(br + ch1);
        }
        __builtin_amdgcn_s_setprio(1);
        #pragma unroll
        for (int mt = 0; mt < 4; ++mt)
            #pragma unroll
            for (int nt = 0; nt < 4; ++nt) {
                acc[mt][nt] = __builtin_amdgcn_mfma_f32_16x16x32_bf16(
                    af0[mt], bf0[nt], acc[mt][nt], 0, 0, 0);
                acc[mt][nt] = __builtin_amdgcn_mfma_f32_16x16x32_bf16(
                    af1[mt], bf1[nt], acc[mt][nt], 0, 0, 0);
            }
        __builtin_amdgcn_s_setprio(0);
    }
#undef STAGE
#undef BDEL

    // ---- epilogue: fused scale/shift + leaky, NCHW fp32 stores ----
    int pob[4];
    #pragma unroll
    for (int nt = 0; nt < 4; ++nt) {
        int pf = pbase + pxb + nt * 16 + l16;
        int bb = pf / HW_;
        pob[nt] = bb * SIZE_ + (pf - bb * HW_);
    }
    #pragma unroll
    for (int mt = 0; mt < 4; ++mt) {
        #pragma unroll
        for (int r = 0; r < 4; ++r) {
            int co = cob + mt * 16 + quad * 4 + r;
            float sc = scale2[co], sh = shift2[co];
            #pragma unroll
            for (int nt = 0; nt < 4; ++nt) {
                float v = acc[mt][nt][r] * sc + sh;
                out[(size_t)pob[nt] + co * HW_] = lrelu(v);
            }
        }
    }
}

// ---------------------------------------------------------------------------
extern "C" void kernel_launch(void* const* d_in, const int* in_sizes, int n_in,
                              void* d_out, int out_size, void* d_ws, size_t ws_size,
                              hipStream_t stream) {
    const float* ax     = (const float*)d_in[0];
    const float* mx     = (const float*)d_in[1];
    const float* cfc    = (const float*)d_in[2];
    const float* bn_g   = (const float*)d_in[3];
    const float* bn_b   = (const float*)d_in[4];
    const float* bn_m   = (const float*)d_in[5];
    const float* bn_v   = (const float*)d_in[6];
    const float* conv_w = (const float*)d_in[7];
    const float* conv_b = (const float*)d_in[8];
    const float* g2     = (const float*)d_in[9];
    const float* b2     = (const float*)d_in[10];
    const float* m2     = (const float*)d_in[11];
    const float* v2     = (const float*)d_in[12];
    float* out = (float*)d_out;

    char* ws = (char*)d_ws;
    // zp2: 4 planes x 6,889,472 B = 27,557,888 B | wA3: 294,912 B | scale2/shift2 | p0/p1/p2
    ushort* zp     = (ushort*)ws;
    ushort* wA     = (ushort*)(ws + 27557888);
    float*  scale2 = (float*)(ws + 27852800);
    float*  shift2 = (float*)(ws + 27853312);
    float*  p0     = (float*)(ws + 27853824);
    float*  p1     = (float*)(ws + 29459456);
    float*  p2     = (float*)(ws + 31065088);

    prep_kernel<<<dim3((SIZE_ + 255) / 256), 256, 0, stream>>>(
        conv_w, conv_b, g2, b2, m2, v2, (const float2*)cfc,
        bn_g, bn_b, bn_m, bn_v, wA, scale2, shift2, p0, p1, p2);
    zfuse_kernel<<<dim3(HP_, B_), 256, 0, stream>>>(
        (const float4*)ax, (const float4*)mx,
        (const float4*)p0, (const float4*)p1, (const float4*)p2, zp);
    conv_kernel<<<dim3(NPIX_ / 256), 512, 0, stream>>>(zp, wA, scale2, shift2, out);
}

// Round 5
// 225.935 us; speedup vs baseline: 1.0700x; 1.0210x over previous
//
#include <hip/hip_runtime.h>

#define B_ 32
#define C_ 128
#define H_ 56
#define W_ 56
#define HW_ (H_*W_)            // 3136
#define SIZE_ (C_*HW_)         // 401408
#define NPIX_ (B_*HW_)         // 100352 = 392 * 256
#define HP_ 58
#define WP_ 58
#define PLSZ_ (B_*HP_*WP_*32)  // 3,444,736 ushort per 32-channel chunk plane
#define K_ 1152                // 9 * 128
#define EPS_ 1e-5f
#define SLOPE_ 0.1f

typedef __bf16 bf16x8 __attribute__((ext_vector_type(8)));
typedef float  f32x4  __attribute__((ext_vector_type(4)));

__device__ __forceinline__ ushort f2bf(float x) {
    union { float f; unsigned u; } v; v.f = x;
    return (ushort)((v.u + 0x7FFFu + ((v.u >> 16) & 1u)) >> 16);   // RNE
}
__device__ __forceinline__ float lrelu(float z) { return z > 0.f ? z : SLOPE_ * z; }

// async global->LDS, 16B per lane; LDS dest = wave-uniform base + lane*16
__device__ __forceinline__ void glds16(const ushort* g, ushort* l) {
    __builtin_amdgcn_global_load_lds(
        (const __attribute__((address_space(1))) unsigned int*)g,
        (__attribute__((address_space(3))) unsigned int*)l, 16, 0, 0);
}

// ---------------------------------------------------------------------------
// prep: repack conv_w -> bf16 wA3[t18][co128][64k]  (K-tile t = k/64: each
// tile's 128x64 A-slice is one contiguous 16KB block); fold bias+BN2;
// fold BN1 into per-position mix params p0,p1,p2.
// ---------------------------------------------------------------------------
__global__ __launch_bounds__(256) void prep_kernel(
    const float* __restrict__ conv_w, const float* __restrict__ conv_b,
    const float* __restrict__ g2, const float* __restrict__ b2,
    const float* __restrict__ m2, const float* __restrict__ v2,
    const float2* __restrict__ cfc, const float* __restrict__ g1,
    const float* __restrict__ b1, const float* __restrict__ mu1,
    const float* __restrict__ v1,
    ushort* __restrict__ wA, float* __restrict__ scale2, float* __restrict__ shift2,
    float* __restrict__ p0, float* __restrict__ p1, float* __restrict__ p2)
{
    int tid = blockIdx.x * 256 + threadIdx.x;
    if (tid < C_ * K_) {
        int co = tid / K_;
        int k  = tid - co * K_;           // k = tap*128 + ci
        int khkw = k >> 7, ci = k & 127;
        int kh = khkw / 3, kw = khkw - 3 * kh;
        wA[((k >> 6) * C_ + co) * 64 + (k & 63)] =
            f2bf(conv_w[((co * C_ + ci) * 3 + kh) * 3 + kw]);
    }
    if (tid < C_) {
        float sc = g2[tid] * rsqrtf(v2[tid] + EPS_);
        scale2[tid] = sc;
        shift2[tid] = (conv_b[tid] - m2[tid]) * sc + b2[tid];
    }
    if (tid < SIZE_) {
        float sc = g1[tid] * rsqrtf(v1[tid] + EPS_);
        float2 wv = cfc[tid];
        p0[tid] = wv.x * sc;
        p1[tid] = wv.y * sc;
        p2[tid] = b1[tid] - mu1[tid] * sc;
    }
}

// ---------------------------------------------------------------------------
// zfuse: z = leaky(a*p0 + m*p1 + p2) -> bf16, FOUR zero-padded 32-channel
// chunk planes zp2[kc][b][hp][wp][32].
// R4 fix: fully unrolled 7-iteration body with ALL 35 float4 loads issued
// BEFORE first use (VGPR 20 -> ~160).  Previous code was load->wait->store
// serialized per iteration (one memory round trip each) -> latency-bound at
// 34% HBM.  35 loads in flight/thread = 560B MLP; computes retire waits
// oldest-first.  Phase-2 write-out unchanged.
// ---------------------------------------------------------------------------
__global__ __launch_bounds__(256) void zfuse_kernel(
    const float4* __restrict__ ax, const float4* __restrict__ mx,
    const float4* __restrict__ p0, const float4* __restrict__ p1,
    const float4* __restrict__ p2, ushort* __restrict__ zp)
{
    __shared__ ushort tile[W_ * 132];   // stride 132: 8B-aligned rows, no 2^k banking
    const int hp = blockIdx.x, b = blockIdx.y;
    const int tid = threadIdx.x;
    const int rb = (b * HP_ + hp) * (WP_ * 32);     // row base (ushort) within a plane
    if (hp == 0 || hp == HP_ - 1) {                 // full zero border rows, all 4 planes
        for (int ks = 0; ks < 4; ++ks) {
            uint2* r2 = (uint2*)(zp + ks * PLSZ_ + rb);
            for (int i = tid; i < WP_ * 32 / 4; i += 256) r2[i] = make_uint2(0u, 0u);
        }
        return;
    }
    const int h = hp - 1;
    const int base4 = (b * SIZE_) >> 2;

    int s4v[7], wbv[7], cv[7];
    #pragma unroll
    for (int u = 0; u < 7; ++u) {              // 1792 = 7*256 exactly
        int i  = tid + u * 256;
        int c  = i / 14;
        int w4 = i - c * 14;
        cv[u]  = c;
        wbv[u] = w4 * 4;
        s4v[u] = c * (HW_ / 4) + h * (W_ / 4) + w4;
    }
    float4 av[7], mv[7], q0v[7], q1v[7], q2v[7];
    #pragma unroll
    for (int u = 0; u < 7; ++u) {              // all 35 loads issued back-to-back
        av[u]  = ax[base4 + s4v[u]];
        mv[u]  = mx[base4 + s4v[u]];
        q0v[u] = p0[s4v[u]];
        q1v[u] = p1[s4v[u]];
        q2v[u] = p2[s4v[u]];
    }
    #pragma unroll
    for (int u = 0; u < 7; ++u) {
        const int c = cv[u], wb = wbv[u];
        tile[(wb + 0) * 132 + c] = f2bf(lrelu(av[u].x * q0v[u].x + mv[u].x * q1v[u].x + q2v[u].x));
        tile[(wb + 1) * 132 + c] = f2bf(lrelu(av[u].y * q0v[u].y + mv[u].y * q1v[u].y + q2v[u].y));
        tile[(wb + 2) * 132 + c] = f2bf(lrelu(av[u].z * q0v[u].z + mv[u].z * q1v[u].z + q2v[u].z));
        tile[(wb + 3) * 132 + c] = f2bf(lrelu(av[u].w * q0v[u].w + mv[u].w * q1v[u].w + q2v[u].w));
    }
    __syncthreads();
    {   // left/right border columns: 4 planes x 32 ch x 2 sides = 256 threads
        int side = (tid >> 7) & 1, ks = (tid >> 5) & 3, cc = tid & 31;
        zp[ks * PLSZ_ + rb + (side ? (WP_ - 1) * 32 : 0) + cc] = 0;
    }
    for (int j = tid; j < 1792; j += 256) {    // 4 planes * 56 w * 8 uint2-chunks
        int ks = j / 448, r = j - ks * 448;
        int w = r >> 3, cc = r & 7;
        *(uint2*)(zp + ks * PLSZ_ + rb + (w + 1) * 32 + cc * 4) =
            *(const uint2*)(tile + w * 132 + ks * 32 + cc * 4);
    }
}

// ---------------------------------------------------------------------------
// conv: implicit GEMM, M=128co x N=100352px x K=1152, bf16 MFMA 16x16x32.
// m201-class deep pipeline: 512 threads (8 waves, 2co x 4px), tile 128x256,
// BK=64 (18 K-tiles), THREE-buffer LDS (144KB, 1 block/CU), one barrier per
// K-tile.  Counted vmcnt(6): stage(t+1) stays in flight across the barrier;
// never drains to 0 in the main loop.  UNCHANGED from R4 (so its true dur_us
// surfaces in top-5 next round once zfuse drops below it).
// ---------------------------------------------------------------------------
__global__ __launch_bounds__(512, 2) void conv_kernel(
    const ushort* __restrict__ zp, const ushort* __restrict__ wA,
    const float* __restrict__ scale2, const float* __restrict__ shift2,
    float* __restrict__ out)
{
    __shared__ ushort As[3][128 * 64];   // 3 x 16 KB
    __shared__ ushort Bs[3][256 * 64];   // 3 x 32 KB

    const int tid  = threadIdx.x;
    const int wave = tid >> 6, lane = tid & 63;
    const int l16  = lane & 15, quad = lane >> 4;
    // XCD swizzle: 392 blocks = 8 XCDs x 49 contiguous
    const int bid  = blockIdx.x;
    const int pbase = ((bid & 7) * 49 + (bid >> 3)) * 256;

    // ---- staging roles ----
    const int c_swz = (lane & 7) ^ ((lane >> 3) & 7);   // physical src chunk
    const ushort* agA = wA + (16 * wave + (lane >> 3)) * 64 + c_swz * 8;

    const ushort* bgB[4];
    #pragma unroll
    for (int j = 0; j < 4; ++j) {
        int pxl = 32 * wave + 8 * j + (lane >> 3);
        int pf  = pbase + pxl;
        int bb  = pf / HW_, pi = pf - bb * HW_;
        int h   = pi / W_, w = pi - h * W_;
        bgB[j] = zp + (c_swz >> 2) * PLSZ_
                    + ((bb * HP_ + h) * WP_ + w) * 32 + (c_swz & 3) * 8;
    }

    // ---- compute roles: wave = 64co x 64px of the 128x256 tile ----
    const int cob = (wave & 1) * 64;
    const int pxb = (wave >> 1) * 64;
    const int ch0 = ((quad ^ (l16 & 7))) * 8;   // ks=0, ushort offset
    const int ch1 = ch0 ^ 32;                   // ks=1

    f32x4 acc[4][4] = {};

#define BDEL(t) (((t) & 1) * 2 * PLSZ_ + \
                 (((((t) >> 1) / 3) * WP_ + (((t) >> 1) % 3)) * 32))

#define STAGE(t, buf) do {                                              \
        glds16(agA + (t) * 8192,        &As[buf][wave * 1024]);         \
        glds16(agA + (t) * 8192 + 512,  &As[buf][wave * 1024 + 512]);   \
        glds16(bgB[0] + BDEL(t), &Bs[buf][wave * 2048]);                \
        glds16(bgB[1] + BDEL(t), &Bs[buf][wave * 2048 + 512]);          \
        glds16(bgB[2] + BDEL(t), &Bs[buf][wave * 2048 + 1024]);         \
        glds16(bgB[3] + BDEL(t), &Bs[buf][wave * 2048 + 1536]);         \
    } while (0)

    STAGE(0, 0);
    STAGE(1, 1);

    #pragma unroll
    for (int t = 0; t < 18; ++t) {
        __builtin_amdgcn_sched_barrier(0);
        if (t < 17) asm volatile("s_waitcnt vmcnt(6)" ::: "memory");
        else        asm volatile("s_waitcnt vmcnt(0)" ::: "memory");
        __builtin_amdgcn_s_barrier();    // all waves' stage(t) now visible
        __builtin_amdgcn_sched_barrier(0);
        if (t <= 15) STAGE(t + 2, (t + 2) % 3);   // buf last read at t-1

        const int buf = t % 3;
        bf16x8 af0[4], af1[4], bf0[4], bf1[4];
        #pragma unroll
        for (int mt = 0; mt < 4; ++mt) {
            const ushort* ar = &As[buf][(cob + mt * 16 + l16) * 64];
            af0[mt] = *(const bf16x8*)(ar + ch0);
            af1[mt] = *(const bf16x8*)(ar + ch1);
        }
        #pragma unroll
        for (int nt = 0; nt < 4; ++nt) {
            const ushort* br = &Bs[buf][(pxb + nt * 16 + l16) * 64];
            bf0[nt] = *(const bf16x8*)(br + ch0);
            bf1[nt] = *(const bf16x8*)(br + ch1);
        }
        __builtin_amdgcn_s_setprio(1);
        #pragma unroll
        for (int mt = 0; mt < 4; ++mt)
            #pragma unroll
            for (int nt = 0; nt < 4; ++nt) {
                acc[mt][nt] = __builtin_amdgcn_mfma_f32_16x16x32_bf16(
                    af0[mt], bf0[nt], acc[mt][nt], 0, 0, 0);
                acc[mt][nt] = __builtin_amdgcn_mfma_f32_16x16x32_bf16(
                    af1[mt], bf1[nt], acc[mt][nt], 0, 0, 0);
            }
        __builtin_amdgcn_s_setprio(0);
    }
#undef STAGE
#undef BDEL

    // ---- epilogue: fused scale/shift + leaky, NCHW fp32 stores ----
    int pob[4];
    #pragma unroll
    for (int nt = 0; nt < 4; ++nt) {
        int pf = pbase + pxb + nt * 16 + l16;
        int bb = pf / HW_;
        pob[nt] = bb * SIZE_ + (pf - bb * HW_);
    }
    #pragma unroll
    for (int mt = 0; mt < 4; ++mt) {
        #pragma unroll
        for (int r = 0; r < 4; ++r) {
            int co = cob + mt * 16 + quad * 4 + r;
            float sc = scale2[co], sh = shift2[co];
            #pragma unroll
            for (int nt = 0; nt < 4; ++nt) {
                float v = acc[mt][nt][r] * sc + sh;
                out[(size_t)pob[nt] + co * HW_] = lrelu(v);
            }
        }
    }
}

// ---------------------------------------------------------------------------
extern "C" void kernel_launch(void* const* d_in, const int* in_sizes, int n_in,
                              void* d_out, int out_size, void* d_ws, size_t ws_size,
                              hipStream_t stream) {
    const float* ax     = (const float*)d_in[0];
    const float* mx     = (const float*)d_in[1];
    const float* cfc    = (const float*)d_in[2];
    const float* bn_g   = (const float*)d_in[3];
    const float* bn_b   = (const float*)d_in[4];
    const float* bn_m   = (const float*)d_in[5];
    const float* bn_v   = (const float*)d_in[6];
    const float* conv_w = (const float*)d_in[7];
    const float* conv_b = (const float*)d_in[8];
    const float* g2     = (const float*)d_in[9];
    const float* b2     = (const float*)d_in[10];
    const float* m2     = (const float*)d_in[11];
    const float* v2     = (const float*)d_in[12];
    float* out = (float*)d_out;

    char* ws = (char*)d_ws;
    // zp2: 4 planes x 6,889,472 B = 27,557,888 B | wA3: 294,912 B | scale2/shift2 | p0/p1/p2
    ushort* zp     = (ushort*)ws;
    ushort* wA     = (ushort*)(ws + 27557888);
    float*  scale2 = (float*)(ws + 27852800);
    float*  shift2 = (float*)(ws + 27853312);
    float*  p0     = (float*)(ws + 27853824);
    float*  p1     = (float*)(ws + 29459456);
    float*  p2     = (float*)(ws + 31065088);

    prep_kernel<<<dim3((SIZE_ + 255) / 256), 256, 0, stream>>>(
        conv_w, conv_b, g2, b2, m2, v2, (const float2*)cfc,
        bn_g, bn_b, bn_m, bn_v, wA, scale2, shift2, p0, p1, p2);
    zfuse_kernel<<<dim3(HP_, B_), 256, 0, stream>>>(
        (const float4*)ax, (const float4*)mx,
        (const float4*)p0, (const float4*)p1, (const float4*)p2, zp);
    conv_kernel<<<dim3(NPIX_ / 256), 512, 0, stream>>>(zp, wA, scale2, shift2, out);
}

// Round 6
// 224.509 us; speedup vs baseline: 1.0768x; 1.0064x over previous
//
#include <hip/hip_runtime.h>

#define B_ 32
#define C_ 128
#define H_ 56
#define W_ 56
#define HW_ (H_*W_)            // 3136
#define SIZE_ (C_*HW_)         // 401408
#define NPIX_ (B_*HW_)         // 100352 = 392 * 256
#define HP_ 58
#define WP_ 58
#define PLSZ_ (B_*HP_*WP_*32)  // 3,444,736 ushort per 32-channel chunk plane
#define K_ 1152                // 9 * 128
#define EPS_ 1e-5f
#define SLOPE_ 0.1f

typedef __bf16 bf16x8 __attribute__((ext_vector_type(8)));
typedef float  f32x4  __attribute__((ext_vector_type(4)));

__device__ __forceinline__ ushort f2bf(float x) {
    union { float f; unsigned u; } v; v.f = x;
    return (ushort)((v.u + 0x7FFFu + ((v.u >> 16) & 1u)) >> 16);   // RNE
}
__device__ __forceinline__ float lrelu(float z) { return z > 0.f ? z : SLOPE_ * z; }

// async global->LDS, 16B per lane; LDS dest = wave-uniform base + lane*16;
// GLOBAL source is per-lane (gather).  Zero VGPR cost -> unlimited MLP.
__device__ __forceinline__ void glds16(const ushort* g, ushort* l) {
    __builtin_amdgcn_global_load_lds(
        (const __attribute__((address_space(1))) unsigned int*)g,
        (__attribute__((address_space(3))) unsigned int*)l, 16, 0, 0);
}

// ---------------------------------------------------------------------------
// prep: repack conv_w -> bf16 wA3[t18][co128][64k]  (K-tile t = k/64: each
// tile's 128x64 A-slice is one contiguous 16KB block); fold bias+BN2;
// fold BN1 into per-position mix params p0,p1,p2.   (unchanged)
// ---------------------------------------------------------------------------
__global__ __launch_bounds__(256) void prep_kernel(
    const float* __restrict__ conv_w, const float* __restrict__ conv_b,
    const float* __restrict__ g2, const float* __restrict__ b2,
    const float* __restrict__ m2, const float* __restrict__ v2,
    const float2* __restrict__ cfc, const float* __restrict__ g1,
    const float* __restrict__ b1, const float* __restrict__ mu1,
    const float* __restrict__ v1,
    ushort* __restrict__ wA, float* __restrict__ scale2, float* __restrict__ shift2,
    float* __restrict__ p0, float* __restrict__ p1, float* __restrict__ p2)
{
    int tid = blockIdx.x * 256 + threadIdx.x;
    if (tid < C_ * K_) {
        int co = tid / K_;
        int k  = tid - co * K_;           // k = tap*128 + ci
        int khkw = k >> 7, ci = k & 127;
        int kh = khkw / 3, kw = khkw - 3 * kh;
        wA[((k >> 6) * C_ + co) * 64 + (k & 63)] =
            f2bf(conv_w[((co * C_ + ci) * 3 + kh) * 3 + kw]);
    }
    if (tid < C_) {
        float sc = g2[tid] * rsqrtf(v2[tid] + EPS_);
        scale2[tid] = sc;
        shift2[tid] = (conv_b[tid] - m2[tid]) * sc + b2[tid];
    }
    if (tid < SIZE_) {
        float sc = g1[tid] * rsqrtf(v1[tid] + EPS_);
        float2 wv = cfc[tid];
        p0[tid] = wv.x * sc;
        p1[tid] = wv.y * sc;
        p2[tid] = b1[tid] - mu1[tid] * sc;
    }
}

// ---------------------------------------------------------------------------
// zfuse v3: z = leaky(a*p0 + m*p1 + p2) -> bf16, FOUR zero-padded 32-channel
// chunk planes zp2[kc][b][hp][wp][32].
// R5 fixes (both latency mechanisms):
//  (1) ax/mx staged to LDS via glds16 gather: per-lane global src, 0 VGPR,
//      14 loads in flight per wave regardless of regalloc -> full MLP.
//      Each wave computes from ITS OWN 32-channel slab: vmcnt(0) only, no
//      barrier between stage and phase-1.
//  (2) flat grid, XCD-swizzled with CONTIGUOUS hp per XCD: row-boundary
//      cache lines (h*224 misalignment) dedupe in-XCD; p0..p2 working set
//      per XCD ~625KB -> L2-resident (was 4.8MB > 4MB/XCD, thrashing).
// p loads stay float4 VGPR loads (L2-hit after swizzle, hidden by unroll).
// LDS: 2x28672 + 14784 = 72128 B -> 2 blocks/CU.
// ---------------------------------------------------------------------------
__global__ __launch_bounds__(256, 4) void zfuse_kernel(
    const float4* __restrict__ ax, const float4* __restrict__ mx,
    const float4* __restrict__ p0, const float4* __restrict__ p1,
    const float4* __restrict__ p2, ushort* __restrict__ zp)
{
    __shared__ float4 axS[4][448];      // 28672 B: [wave][c_loc*14 + w4]
    __shared__ float4 mxS[4][448];      // 28672 B
    __shared__ ushort tile[W_ * 132];   // 14784 B: stride 132, transposed z

    const int tid = threadIdx.x;
    // XCD swizzle: 1856 = 8 x 232; each XCD gets contiguous hp-chunk (all b)
    const int wg  = blockIdx.x;
    const int swz = (wg & 7) * 232 + (wg >> 3);
    const int hp  = swz >> 5;           // hp-major
    const int b   = swz & 31;
    const int rb  = (b * HP_ + hp) * (WP_ * 32);    // row base within a plane

    if (hp == 0 || hp == HP_ - 1) {     // full zero border rows, all 4 planes
        for (int ks = 0; ks < 4; ++ks) {
            uint2* r2 = (uint2*)(zp + ks * PLSZ_ + rb);
            for (int i = tid; i < WP_ * 32 / 4; i += 256) r2[i] = make_uint2(0u, 0u);
        }
        return;
    }
    const int h  = hp - 1;
    const int wv = tid >> 6, l = tid & 63;
    const int base4 = b * (SIZE_ / 4);
    const int hb4   = h * (W_ / 4);     // h*14

    // ---- stage: wave wv gathers its 32-channel slab of ax,mx (14 glds16) ----
    #pragma unroll
    for (int j = 0; j < 7; ++j) {
        int i  = j * 64 + l;            // 448 float4s per slab, exact
        int cl = i / 14, w4 = i - cl * 14;
        int s4 = (wv * 32 + cl) * (HW_ / 4) + hb4 + w4;
        glds16((const ushort*)(ax + base4 + s4), (ushort*)&axS[wv][j * 64]);
        glds16((const ushort*)(mx + base4 + s4), (ushort*)&mxS[wv][j * 64]);
    }
    asm volatile("s_waitcnt vmcnt(0)" ::: "memory");
    __builtin_amdgcn_sched_barrier(0);  // rule 18: no hoist past inline-asm wait

    // ---- phase 1: own slab -> transposed bf16 tile ----
    #pragma unroll
    for (int u = 0; u < 7; ++u) {
        int i  = u * 64 + l;
        int cl = i / 14, w4 = i - cl * 14;
        int c  = wv * 32 + cl;
        int s4 = c * (HW_ / 4) + hb4 + w4;
        float4 a  = axS[wv][i];
        float4 m  = mxS[wv][i];
        float4 q0 = p0[s4], q1 = p1[s4], q2 = p2[s4];
        int wb = w4 * 4;
        tile[(wb + 0) * 132 + c] = f2bf(lrelu(a.x * q0.x + m.x * q1.x + q2.x));
        tile[(wb + 1) * 132 + c] = f2bf(lrelu(a.y * q0.y + m.y * q1.y + q2.y));
        tile[(wb + 2) * 132 + c] = f2bf(lrelu(a.z * q0.z + m.z * q1.z + q2.z));
        tile[(wb + 3) * 132 + c] = f2bf(lrelu(a.w * q0.w + m.w * q1.w + q2.w));
    }
    __syncthreads();

    {   // left/right border columns: 4 planes x 32 ch x 2 sides = 256 threads
        int side = (tid >> 7) & 1, ks = (tid >> 5) & 3, cc = tid & 31;
        zp[ks * PLSZ_ + rb + (side ? (WP_ - 1) * 32 : 0) + cc] = 0;
    }
    for (int j = tid; j < 1792; j += 256) {    // 4 planes * 56 w * 8 uint2-chunks
        int ks = j / 448, r = j - ks * 448;
        int w = r >> 3, cc = r & 7;
        *(uint2*)(zp + ks * PLSZ_ + rb + (w + 1) * 32 + cc * 4) =
            *(const uint2*)(tile + w * 132 + ks * 32 + cc * 4);
    }
}

// ---------------------------------------------------------------------------
// conv: implicit GEMM, M=128co x N=100352px x K=1152, bf16 MFMA 16x16x32.
// m201-class deep pipeline: 512 threads (8 waves, 2co x 4px), tile 128x256,
// BK=64 (18 K-tiles), THREE-buffer LDS (144KB, 1 block/CU), one barrier per
// K-tile, counted vmcnt(6).  UNCHANGED from R4.
// ---------------------------------------------------------------------------
__global__ __launch_bounds__(512, 2) void conv_kernel(
    const ushort* __restrict__ zp, const ushort* __restrict__ wA,
    const float* __restrict__ scale2, const float* __restrict__ shift2,
    float* __restrict__ out)
{
    __shared__ ushort As[3][128 * 64];   // 3 x 16 KB
    __shared__ ushort Bs[3][256 * 64];   // 3 x 32 KB

    const int tid  = threadIdx.x;
    const int wave = tid >> 6, lane = tid & 63;
    const int l16  = lane & 15, quad = lane >> 4;
    // XCD swizzle: 392 blocks = 8 XCDs x 49 contiguous
    const int bid  = blockIdx.x;
    const int pbase = ((bid & 7) * 49 + (bid >> 3)) * 256;

    // ---- staging roles ----
    const int c_swz = (lane & 7) ^ ((lane >> 3) & 7);   // physical src chunk
    const ushort* agA = wA + (16 * wave + (lane >> 3)) * 64 + c_swz * 8;

    const ushort* bgB[4];
    #pragma unroll
    for (int j = 0; j < 4; ++j) {
        int pxl = 32 * wave + 8 * j + (lane >> 3);
        int pf  = pbase + pxl;
        int bb  = pf / HW_, pi = pf - bb * HW_;
        int h   = pi / W_, w = pi - h * W_;
        bgB[j] = zp + (c_swz >> 2) * PLSZ_
                    + ((bb * HP_ + h) * WP_ + w) * 32 + (c_swz & 3) * 8;
    }

    // ---- compute roles: wave = 64co x 64px of the 128x256 tile ----
    const int cob = (wave & 1) * 64;
    const int pxb = (wave >> 1) * 64;
    const int ch0 = ((quad ^ (l16 & 7))) * 8;   // ks=0, ushort offset
    const int ch1 = ch0 ^ 32;                   // ks=1

    f32x4 acc[4][4] = {};

#define BDEL(t) (((t) & 1) * 2 * PLSZ_ + \
                 (((((t) >> 1) / 3) * WP_ + (((t) >> 1) % 3)) * 32))

#define STAGE(t, buf) do {                                              \
        glds16(agA + (t) * 8192,        &As[buf][wave * 1024]);         \
        glds16(agA + (t) * 8192 + 512,  &As[buf][wave * 1024 + 512]);   \
        glds16(bgB[0] + BDEL(t), &Bs[buf][wave * 2048]);                \
        glds16(bgB[1] + BDEL(t), &Bs[buf][wave * 2048 + 512]);          \
        glds16(bgB[2] + BDEL(t), &Bs[buf][wave * 2048 + 1024]);         \
        glds16(bgB[3] + BDEL(t), &Bs[buf][wave * 2048 + 1536]);         \
    } while (0)

    STAGE(0, 0);
    STAGE(1, 1);

    #pragma unroll
    for (int t = 0; t < 18; ++t) {
        __builtin_amdgcn_sched_barrier(0);
        if (t < 17) asm volatile("s_waitcnt vmcnt(6)" ::: "memory");
        else        asm volatile("s_waitcnt vmcnt(0)" ::: "memory");
        __builtin_amdgcn_s_barrier();    // all waves' stage(t) now visible
        __builtin_amdgcn_sched_barrier(0);
        if (t <= 15) STAGE(t + 2, (t + 2) % 3);   // buf last read at t-1

        const int buf = t % 3;
        bf16x8 af0[4], af1[4], bf0[4], bf1[4];
        #pragma unroll
        for (int mt = 0; mt < 4; ++mt) {
            const ushort* ar = &As[buf][(cob + mt * 16 + l16) * 64];
            af0[mt] = *(const bf16x8*)(ar + ch0);
            af1[mt] = *(const bf16x8*)(ar + ch1);
        }
        #pragma unroll
        for (int nt = 0; nt < 4; ++nt) {
            const ushort* br = &Bs[buf][(pxb + nt * 16 + l16) * 64];
            bf0[nt] = *(const bf16x8*)(br + ch0);
            bf1[nt] = *(const bf16x8*)(br + ch1);
        }
        __builtin_amdgcn_s_setprio(1);
        #pragma unroll
        for (int mt = 0; mt < 4; ++mt)
            #pragma unroll
            for (int nt = 0; nt < 4; ++nt) {
                acc[mt][nt] = __builtin_amdgcn_mfma_f32_16x16x32_bf16(
                    af0[mt], bf0[nt], acc[mt][nt], 0, 0, 0);
                acc[mt][nt] = __builtin_amdgcn_mfma_f32_16x16x32_bf16(
                    af1[mt], bf1[nt], acc[mt][nt], 0, 0, 0);
            }
        __builtin_amdgcn_s_setprio(0);
    }
#undef STAGE
#undef BDEL

    // ---- epilogue: fused scale/shift + leaky, NCHW fp32 stores ----
    int pob[4];
    #pragma unroll
    for (int nt = 0; nt < 4; ++nt) {
        int pf = pbase + pxb + nt * 16 + l16;
        int bb = pf / HW_;
        pob[nt] = bb * SIZE_ + (pf - bb * HW_);
    }
    #pragma unroll
    for (int mt = 0; mt < 4; ++mt) {
        #pragma unroll
        for (int r = 0; r < 4; ++r) {
            int co = cob + mt * 16 + quad * 4 + r;
            float sc = scale2[co], sh = shift2[co];
            #pragma unroll
            for (int nt = 0; nt < 4; ++nt) {
                float v = acc[mt][nt][r] * sc + sh;
                out[(size_t)pob[nt] + co * HW_] = lrelu(v);
            }
        }
    }
}

// ---------------------------------------------------------------------------
extern "C" void kernel_launch(void* const* d_in, const int* in_sizes, int n_in,
                              void* d_out, int out_size, void* d_ws, size_t ws_size,
                              hipStream_t stream) {
    const float* ax     = (const float*)d_in[0];
    const float* mx     = (const float*)d_in[1];
    const float* cfc    = (const float*)d_in[2];
    const float* bn_g   = (const float*)d_in[3];
    const float* bn_b   = (const float*)d_in[4];
    const float* bn_m   = (const float*)d_in[5];
    const float* bn_v   = (const float*)d_in[6];
    const float* conv_w = (const float*)d_in[7];
    const float* conv_b = (const float*)d_in[8];
    const float* g2     = (const float*)d_in[9];
    const float* b2     = (const float*)d_in[10];
    const float* m2     = (const float*)d_in[11];
    const float* v2     = (const float*)d_in[12];
    float* out = (float*)d_out;

    char* ws = (char*)d_ws;
    // zp2: 4 planes x 6,889,472 B = 27,557,888 B | wA3: 294,912 B | scale2/shift2 | p0/p1/p2
    ushort* zp     = (ushort*)ws;
    ushort* wA     = (ushort*)(ws + 27557888);
    float*  scale2 = (float*)(ws + 27852800);
    float*  shift2 = (float*)(ws + 27853312);
    float*  p0     = (float*)(ws + 27853824);
    float*  p1     = (float*)(ws + 29459456);
    float*  p2     = (float*)(ws + 31065088);

    prep_kernel<<<dim3((SIZE_ + 255) / 256), 256, 0, stream>>>(
        conv_w, conv_b, g2, b2, m2, v2, (const float2*)cfc,
        bn_g, bn_b, bn_m, bn_v, wA, scale2, shift2, p0, p1, p2);
    zfuse_kernel<<<dim3(HP_ * B_), 256, 0, stream>>>(
        (const float4*)ax, (const float4*)mx,
        (const float4*)p0, (const float4*)p1, (const float4*)p2, zp);
    conv_kernel<<<dim3(NPIX_ / 256), 512, 0, stream>>>(zp, wA, scale2, shift2, out);
}